// Round 7
// baseline (565.904 us; speedup 1.0000x reference)
//
#include <hip/hip_runtime.h>
#include <cfloat>

#define D 64
#define K 512
#define MARGIN 1.5e-4f
#define WL_CAP 65536

typedef __attribute__((ext_vector_type(8))) short bf16x8;
typedef __attribute__((ext_vector_type(4))) float f32x4;

__device__ __forceinline__ short f2bf(float x) {          // fp32 -> bf16 RNE
    unsigned u = __float_as_uint(x);
    u += 0x7fffu + ((u >> 16) & 1u);
    return (short)(u >> 16);
}
__device__ __forceinline__ float bf2f(short s) {
    return __uint_as_float(((unsigned)(unsigned short)s) << 16);
}

__device__ __forceinline__ void gload_lds16(const void* g, void* l) {
    __builtin_amdgcn_global_load_lds(
        (const __attribute__((address_space(1))) unsigned int*)g,
        (__attribute__((address_space(3))) unsigned int*)l, 16, 0, 0);
}

// ===========================================================================
// numpy-bit-exact helpers (VERIFIED bit-match R3-R6: absmax 0.0)
// ===========================================================================
__device__ __forceinline__ float np_pairwise64_sq(const float* a) {
    float r[8];
    #pragma unroll
    for (int j = 0; j < 8; ++j) r[j] = __fmul_rn(a[j], a[j]);
    #pragma unroll
    for (int i = 8; i < 64; i += 8) {
        #pragma unroll
        for (int j = 0; j < 8; ++j)
            r[j] = __fadd_rn(r[j], __fmul_rn(a[i + j], a[i + j]));
    }
    return __fadd_rn(__fadd_rn(__fadd_rn(r[0], r[1]), __fadd_rn(r[2], r[3])),
                     __fadd_rn(__fadd_rn(r[4], r[5]), __fadd_rn(r[6], r[7])));
}

__device__ __forceinline__ float np_seqfma_dot64(const float* x, const float* y) {
    float acc = 0.f;
    #pragma unroll
    for (int d = 0; d < 64; ++d) acc = __fmaf_rn(x[d], y[d], acc);
    return acc;
}

// ===========================================================================
// Kernel E: ee[k] = numpy-bit np.sum(emb[k]*emb[k]); also zeroes the
// worklist counter (runs first on the stream every launch -> deterministic).
// ===========================================================================
__global__ void vq_ee_np_kernel(const float* __restrict__ emb,
                                float* __restrict__ ee, int* __restrict__ wl_cnt) {
    if (threadIdx.x == 0) *wl_cnt = 0;
    const int k = threadIdx.x;            // 512 threads, 1 block
    float e[64];
    const float4* e4 = reinterpret_cast<const float4*>(emb) + k * 16;
    #pragma unroll
    for (int j = 0; j < 16; ++j) {
        float4 t = e4[j];
        e[4*j] = t.x; e[4*j+1] = t.y; e[4*j+2] = t.z; e[4*j+3] = t.w;
    }
    ee[k] = np_pairwise64_sq(e);
}

// ===========================================================================
// Kernel P: one-time bf16 hi/lo split of E in MFMA-fragment order
// ehl[ch][ct][p][lane][8]  (p: 0=hi k0, 1=hi k1, 2=lo k0, 3=lo k1).
// ===========================================================================
__global__ void vq_prep_kernel(const float* __restrict__ emb, short* __restrict__ ehl) {
    const int gid = blockIdx.x * 256 + threadIdx.x;   // 8192 threads
    const int l  = gid & 63;
    const int p  = (gid >> 6) & 3;
    const int code = ((gid >> 11) << 7) + (((gid >> 8) & 7) << 4) + (l & 15);
    const int d0 = ((p & 1) << 5) + ((l >> 4) << 3);
    const float4 v0 = *(const float4*)(emb + code * D + d0);
    const float4 v1 = *(const float4*)(emb + code * D + d0 + 4);
    const float f[8] = {v0.x, v0.y, v0.z, v0.w, v1.x, v1.y, v1.z, v1.w};
    bf16x8 o;
    #pragma unroll
    for (int j = 0; j < 8; ++j) {
        const short h = f2bf(f[j]);
        o[j] = (p < 2) ? h : f2bf(f[j] - bf2f(h));
    }
    *(bf16x8*)(ehl + (long long)gid * 8) = o;
}

// ===========================================================================
// Kernel A: MFMA score pass (G = zh.eh + zh.el + zl.eh, bit-identical fast
// path to verified R5/R6). Restructured for occupancy: 2 A-tiles/wave,
// single 32KB LDS buffer, <=128 total regs -> 4 waves/SIMD (vs 2).
// Branchless min1/min2 via fmed3. Flagged rows appended to worklist.
// ===========================================================================
__global__ __launch_bounds__(256, 4) void vq_score_mfma_kernel(
    const float* __restrict__ z, const short* __restrict__ ehl,
    const float* __restrict__ ee, int* __restrict__ idx,
    int* __restrict__ wl, int* __restrict__ wl_cnt)
{
    __shared__ short eB[16384];       // 32 KB single buffer

    const int t  = threadIdx.x;
    const int l  = t & 63;
    const int w  = t >> 6;            // wave 0..3
    const int kg = l >> 4;
    const int cl = l & 15;

    const long long wbase = (long long)blockIdx.x * 128 + w * 32;

    // ---- stage chunk 0 (latency hidden under A-fragment build)
    {
        const short* src = ehl + w * 4096 + l * 8;
        #pragma unroll
        for (int i = 0; i < 8; ++i)
            gload_lds16(src + i * 512, &eB[w * 4096 + i * 512]);
    }

    // ---- A fragments: 2 tiles x (hi k0, hi k1, lo k0, lo k1)
    bf16x8 aH0[2], aH1[2], aL0[2], aL1[2];
    #pragma unroll
    for (int a = 0; a < 2; ++a) {
        const float* zr = z + (wbase + a * 16 + cl) * D;
        const float4 v0 = *(const float4*)(zr + kg * 8);
        const float4 v1 = *(const float4*)(zr + kg * 8 + 4);
        const float4 v2 = *(const float4*)(zr + 32 + kg * 8);
        const float4 v3 = *(const float4*)(zr + 32 + kg * 8 + 4);
        const float d0[8] = {v0.x,v0.y,v0.z,v0.w,v1.x,v1.y,v1.z,v1.w};
        const float d1[8] = {v2.x,v2.y,v2.z,v2.w,v3.x,v3.y,v3.z,v3.w};
        #pragma unroll
        for (int i = 0; i < 8; ++i) {
            const short h = f2bf(d0[i]); aH0[a][i] = h; aL0[a][i] = f2bf(d0[i] - bf2f(h));
            const short g = f2bf(d1[i]); aH1[a][i] = g; aL1[a][i] = f2bf(d1[i] - bf2f(g));
        }
    }

    float m1[2][4], m2[2][4]; int bi[2][4];
    #pragma unroll
    for (int a = 0; a < 2; ++a)
        #pragma unroll
        for (int r = 0; r < 4; ++r) { m1[a][r] = FLT_MAX; m2[a][r] = FLT_MAX; bi[a][r] = 0; }

    for (int ch = 0; ch < 4; ++ch) {
        if (ch) {
            __syncthreads();          // all waves done reading eB (WAR)
            const short* src = ehl + ch * 16384 + w * 4096 + l * 8;
            #pragma unroll
            for (int i = 0; i < 8; ++i)
                gload_lds16(src + i * 512, &eB[w * 4096 + i * 512]);
        }
        float ekr[8];
        #pragma unroll
        for (int ct = 0; ct < 8; ++ct) ekr[ct] = ee[ch * 128 + ct * 16 + cl];
        __syncthreads();              // staging drained (vmcnt 0 + barrier)

        #pragma unroll
        for (int ct = 0; ct < 8; ++ct) {
            const short* fb = &eB[ct * 2048];
            const bf16x8 b0 = *(const bf16x8*)(fb +       l * 8);
            const bf16x8 b1 = *(const bf16x8*)(fb + 512 + l * 8);
            const bf16x8 b2 = *(const bf16x8*)(fb + 1024 + l * 8);
            const bf16x8 b3 = *(const bf16x8*)(fb + 1536 + l * 8);

            f32x4 acc0 = {0.f, 0.f, 0.f, 0.f};
            f32x4 acc1 = {0.f, 0.f, 0.f, 0.f};
            acc0 = __builtin_amdgcn_mfma_f32_16x16x32_bf16(aH0[0], b0, acc0, 0, 0, 0);
            acc1 = __builtin_amdgcn_mfma_f32_16x16x32_bf16(aH0[1], b0, acc1, 0, 0, 0);
            acc0 = __builtin_amdgcn_mfma_f32_16x16x32_bf16(aH1[0], b1, acc0, 0, 0, 0);
            acc1 = __builtin_amdgcn_mfma_f32_16x16x32_bf16(aH1[1], b1, acc1, 0, 0, 0);
            acc0 = __builtin_amdgcn_mfma_f32_16x16x32_bf16(aH0[0], b2, acc0, 0, 0, 0);
            acc1 = __builtin_amdgcn_mfma_f32_16x16x32_bf16(aH0[1], b2, acc1, 0, 0, 0);
            acc0 = __builtin_amdgcn_mfma_f32_16x16x32_bf16(aH1[0], b3, acc0, 0, 0, 0);
            acc1 = __builtin_amdgcn_mfma_f32_16x16x32_bf16(aH1[1], b3, acc1, 0, 0, 0);
            acc0 = __builtin_amdgcn_mfma_f32_16x16x32_bf16(aL0[0], b0, acc0, 0, 0, 0);
            acc1 = __builtin_amdgcn_mfma_f32_16x16x32_bf16(aL0[1], b0, acc1, 0, 0, 0);
            acc0 = __builtin_amdgcn_mfma_f32_16x16x32_bf16(aL1[0], b1, acc0, 0, 0, 0);
            acc1 = __builtin_amdgcn_mfma_f32_16x16x32_bf16(aL1[1], b1, acc1, 0, 0, 0);

            const int code = ch * 128 + ct * 16 + cl;
            #pragma unroll
            for (int r = 0; r < 4; ++r) {
                const float s0 = __fmaf_rn(-2.0f, acc0[r], ekr[ct]);
                m2[0][r] = __builtin_amdgcn_fmed3f(m1[0][r], m2[0][r], s0);
                bi[0][r] = (s0 < m1[0][r]) ? code : bi[0][r];
                m1[0][r] = fminf(m1[0][r], s0);
                const float s1 = __fmaf_rn(-2.0f, acc1[r], ekr[ct]);
                m2[1][r] = __builtin_amdgcn_fmed3f(m1[1][r], m2[1][r], s1);
                bi[1][r] = (s1 < m1[1][r]) ? code : bi[1][r];
                m1[1][r] = fminf(m1[1][r], s1);
            }
        }
    }

    // merge (m1,m2,bi) across the 16 cl-lanes of each kg group
    #pragma unroll
    for (int a = 0; a < 2; ++a) {
        #pragma unroll
        for (int r = 0; r < 4; ++r) {
            #pragma unroll
            for (int off = 1; off < 16; off <<= 1) {
                const float om1 = __shfl_xor(m1[a][r], off);
                const float om2 = __shfl_xor(m2[a][r], off);
                const int   ob  = __shfl_xor(bi[a][r], off);
                if (om1 < m1[a][r] || (om1 == m1[a][r] && ob < bi[a][r])) {
                    m2[a][r] = fminf(m1[a][r], om2);
                    m1[a][r] = om1; bi[a][r] = ob;
                } else {
                    m2[a][r] = fminf(m2[a][r], om1);
                }
            }
        }
    }

    if (cl == 0) {
        #pragma unroll
        for (int a = 0; a < 2; ++a)
            #pragma unroll
            for (int r = 0; r < 4; ++r) {
                const long long row = wbase + a * 16 + kg * 4 + r;   // D-row map (HW-verified)
                idx[row] = bi[a][r];
                if (m2[a][r] - m1[a][r] < MARGIN) {
                    const int pos = atomicAdd(wl_cnt, 1);
                    if (pos < WL_CAP) wl[pos] = (int)row;
                }
            }
    }
}

// ===========================================================================
// Kernel C: numpy-bit-exact re-resolution, worklist-driven. 2048 waves
// grid-stride over flagged rows; per row, lane handles codes k=64*i+lane.
// ===========================================================================
__global__ __launch_bounds__(256, 4) void vq_refine_np_kernel(
    const float* __restrict__ z, const float* __restrict__ emb,
    const float* __restrict__ ee, const int* __restrict__ wl,
    const int* __restrict__ wl_cnt, int* __restrict__ idx)
{
    const int lane = threadIdx.x & 63;
    const int wid  = blockIdx.x * 4 + (threadIdx.x >> 6);
    const int nW   = gridDim.x * 4;
    const int cnt  = min(*wl_cnt, WL_CAP);

    for (int i = wid; i < cnt; i += nW) {
        const long long r = wl[i];

        float za[64];
        const float4* z4 = reinterpret_cast<const float4*>(z + r * D);
        #pragma unroll
        for (int j = 0; j < 16; ++j) {
            float4 tt = z4[j];
            za[4*j] = tt.x; za[4*j+1] = tt.y; za[4*j+2] = tt.z; za[4*j+3] = tt.w;
        }
        const float zz = np_pairwise64_sq(za);

        float best = FLT_MAX; int bk = 0x7fffffff;
        #pragma unroll 2
        for (int i8 = 0; i8 < 8; ++i8) {
            const int k = (i8 << 6) + lane;          // ascending per lane
            float eb[64];
            const float4* e4 = reinterpret_cast<const float4*>(emb) + k * 16;
            #pragma unroll
            for (int j = 0; j < 16; ++j) {
                float4 tt = e4[j];
                eb[4*j] = tt.x; eb[4*j+1] = tt.y; eb[4*j+2] = tt.z; eb[4*j+3] = tt.w;
            }
            const float G = np_seqfma_dot64(za, eb);
            const float dist = __fadd_rn(__fsub_rn(zz, __fmul_rn(2.0f, G)), ee[k]);
            if (dist < best) { best = dist; bk = k; }
        }
        // cross-lane min, lowest-k tie-break (== numpy first-min)
        #pragma unroll
        for (int off = 32; off; off >>= 1) {
            const float ob = __shfl_xor(best, off);
            const int   ok = __shfl_xor(bk, off);
            if (ob < best || (ob == best && ok < bk)) { best = ob; bk = ok; }
        }
        if (lane == 0) idx[r] = bk;
    }
}

// ===========================================================================
// Kernel B: gather codebook rows, write BOTH tuple outputs (float4).
// ===========================================================================
__global__ void vq_gather_kernel(const float* __restrict__ emb,
                                 const int* __restrict__ idx,
                                 float* __restrict__ out, long long nRows)
{
    const long long c = (long long)blockIdx.x * blockDim.x + threadIdx.x;
    const long long total = nRows * 16;
    if (c >= total) return;
    const long long r = c >> 4;
    const int j = (int)(c & 15);
    const int k = idx[r];
    const float4 val = reinterpret_cast<const float4*>(emb)[k * 16 + j];
    float4* o = reinterpret_cast<float4*>(out);
    o[c] = val;
    o[c + total] = val;
}

// ===========================================================================
extern "C" void kernel_launch(void* const* d_in, const int* in_sizes, int n_in,
                              void* d_out, int out_size, void* d_ws, size_t ws_size,
                              hipStream_t stream) {
    const float* z   = (const float*)d_in[0];   // [N, 64] fp32
    const float* emb = (const float*)d_in[1];   // [512, 64] fp32
    float* out = (float*)d_out;                 // 2 x [N, 64] fp32

    const long long nRows = (long long)in_sizes[0] / D;       // 524288

    char* p = (char*)d_ws;
    int*   idx    = (int*)p;                                      // 2 MB
    float* ee     = (float*)(p + nRows * 4);                      // 2 KB
    short* ehl    = (short*)(p + nRows * 4 + 4096);               // 128 KB
    int*   wl_cnt = (int*)(p + nRows * 4 + 4096 + 131072);        // 4 B
    int*   wl     = (int*)(p + nRows * 4 + 4096 + 131072 + 256);  // 256 KB

    vq_ee_np_kernel<<<1, 512, 0, stream>>>(emb, ee, wl_cnt);
    vq_prep_kernel<<<32, 256, 0, stream>>>(emb, ehl);

    const int scoreBlocks = (int)(nRows / 128);               // 4096
    vq_score_mfma_kernel<<<scoreBlocks, 256, 0, stream>>>(z, ehl, ee, idx, wl, wl_cnt);

    vq_refine_np_kernel<<<512, 256, 0, stream>>>(z, emb, ee, wl, wl_cnt, idx);

    const long long chunks = nRows * 16;
    const int gatherBlocks = (int)((chunks + 255) / 256);     // 32768
    vq_gather_kernel<<<gatherBlocks, 256, 0, stream>>>(emb, idx, out, nRows);
}

// Round 8
// 373.527 us; speedup vs baseline: 1.5150x; 1.5150x over previous
//
#include <hip/hip_runtime.h>
#include <cfloat>

#define D 64
#define K 512
#define MARGIN 1.5e-4f
#define WL_CAP 65536

typedef __attribute__((ext_vector_type(8))) short bf16x8;
typedef __attribute__((ext_vector_type(4))) float f32x4;

__device__ __forceinline__ short f2bf(float x) {          // fp32 -> bf16 RNE
    unsigned u = __float_as_uint(x);
    u += 0x7fffu + ((u >> 16) & 1u);
    return (short)(u >> 16);
}
__device__ __forceinline__ float bf2f(short s) {
    return __uint_as_float(((unsigned)(unsigned short)s) << 16);
}

__device__ __forceinline__ void gload_lds16(const void* g, void* l) {
    __builtin_amdgcn_global_load_lds(
        (const __attribute__((address_space(1))) unsigned int*)g,
        (__attribute__((address_space(3))) unsigned int*)l, 16, 0, 0);
}

// ===========================================================================
// numpy-bit-exact helpers (VERIFIED bit-match R3-R7: absmax 0.0)
// ===========================================================================
__device__ __forceinline__ float np_pairwise64_sq(const float* a) {
    float r[8];
    #pragma unroll
    for (int j = 0; j < 8; ++j) r[j] = __fmul_rn(a[j], a[j]);
    #pragma unroll
    for (int i = 8; i < 64; i += 8) {
        #pragma unroll
        for (int j = 0; j < 8; ++j)
            r[j] = __fadd_rn(r[j], __fmul_rn(a[i + j], a[i + j]));
    }
    return __fadd_rn(__fadd_rn(__fadd_rn(r[0], r[1]), __fadd_rn(r[2], r[3])),
                     __fadd_rn(__fadd_rn(r[4], r[5]), __fadd_rn(r[6], r[7])));
}

__device__ __forceinline__ float np_seqfma_dot64(const float* x, const float* y) {
    float acc = 0.f;
    #pragma unroll
    for (int d = 0; d < 64; ++d) acc = __fmaf_rn(x[d], y[d], acc);
    return acc;
}

// ===========================================================================
// Kernel E: ee[k] = numpy-bit np.sum(emb[k]*emb[k]); zeroes worklist counter.
// ===========================================================================
__global__ void vq_ee_np_kernel(const float* __restrict__ emb,
                                float* __restrict__ ee, int* __restrict__ wl_cnt) {
    if (threadIdx.x == 0) *wl_cnt = 0;
    const int k = threadIdx.x;            // 512 threads, 1 block
    float e[64];
    const float4* e4 = reinterpret_cast<const float4*>(emb) + k * 16;
    #pragma unroll
    for (int j = 0; j < 16; ++j) {
        float4 t = e4[j];
        e[4*j] = t.x; e[4*j+1] = t.y; e[4*j+2] = t.z; e[4*j+3] = t.w;
    }
    ee[k] = np_pairwise64_sq(e);
}

// ===========================================================================
// Kernel P: one-time bf16 hi/lo split of E in MFMA-fragment order
// ehl[ch][ct][p][lane][8]  (p: 0=hi d0-31, 1=hi d32-63, 2=lo d0-31, 3=lo d32-63)
// ===========================================================================
__global__ void vq_prep_kernel(const float* __restrict__ emb, short* __restrict__ ehl) {
    const int gid = blockIdx.x * 256 + threadIdx.x;   // 8192 threads
    const int l  = gid & 63;
    const int p  = (gid >> 6) & 3;
    const int code = ((gid >> 11) << 7) + (((gid >> 8) & 7) << 4) + (l & 15);
    const int d0 = ((p & 1) << 5) + ((l >> 4) << 3);
    const float4 v0 = *(const float4*)(emb + code * D + d0);
    const float4 v1 = *(const float4*)(emb + code * D + d0 + 4);
    const float f[8] = {v0.x, v0.y, v0.z, v0.w, v1.x, v1.y, v1.z, v1.w};
    bf16x8 o;
    #pragma unroll
    for (int j = 0; j < 8; ++j) {
        const short h = f2bf(f[j]);
        o[j] = (p < 2) ? h : f2bf(f[j] - bf2f(h));
    }
    *(bf16x8*)(ehl + (long long)gid * 8) = o;
}

// ===========================================================================
// Kernel A: MFMA score pass (G = zh.eh + zh.el + zl.eh, fast path identical
// to verified R5-R7). 512 thr = 8 waves, 2 A-tiles/wave (256 rows/block).
// Double-buffered 2x32KB LDS, one barrier per chunk; staging overlaps the
// full compute phase. launch_bounds(512,2): 256-reg cap -> no forced spill;
// ~100 regs used -> 16 waves/CU (2 blocks, LDS 66KB/block).
// ===========================================================================
__global__ __launch_bounds__(512, 2) void vq_score_mfma_kernel(
    const float* __restrict__ z, const short* __restrict__ ehl,
    const float* __restrict__ ee, int* __restrict__ idx,
    int* __restrict__ wl, int* __restrict__ wl_cnt)
{
    __shared__ short eB[2][16384];    // 2 x 32 KB double buffer
    __shared__ float eeL[512];        // 2 KB

    const int t  = threadIdx.x;
    const int l  = t & 63;
    const int w  = t >> 6;            // wave 0..7
    const int kg = l >> 4;
    const int cl = l & 15;

    const long long wbase = (long long)blockIdx.x * 256 + w * 32;

    // ---- stage chunk 0 (latency hidden under A-fragment build)
    {
        const short* src = ehl + w * 2048 + l * 8;
        short* dst = &eB[0][w * 2048 + l * 8];
        #pragma unroll
        for (int i = 0; i < 4; ++i)
            gload_lds16(src + i * 512, dst + i * 512);
    }
    eeL[t] = ee[t];                   // 512 threads, 1 each

    // ---- A fragments: 2 tiles x (hi d0-31, hi d32-63, lo d0-31, lo d32-63)
    bf16x8 aH0[2], aH1[2], aL0[2], aL1[2];
    #pragma unroll
    for (int a = 0; a < 2; ++a) {
        const float* zr = z + (wbase + a * 16 + cl) * D;
        const float4 v0 = *(const float4*)(zr + kg * 8);
        const float4 v1 = *(const float4*)(zr + kg * 8 + 4);
        const float4 v2 = *(const float4*)(zr + 32 + kg * 8);
        const float4 v3 = *(const float4*)(zr + 32 + kg * 8 + 4);
        const float d0[8] = {v0.x,v0.y,v0.z,v0.w,v1.x,v1.y,v1.z,v1.w};
        const float d1[8] = {v2.x,v2.y,v2.z,v2.w,v3.x,v3.y,v3.z,v3.w};
        #pragma unroll
        for (int i = 0; i < 8; ++i) {
            const short h = f2bf(d0[i]); aH0[a][i] = h; aL0[a][i] = f2bf(d0[i] - bf2f(h));
            const short g = f2bf(d1[i]); aH1[a][i] = g; aL1[a][i] = f2bf(d1[i] - bf2f(g));
        }
    }

    float m1[2][4], m2[2][4]; int bi[2][4];
    #pragma unroll
    for (int a = 0; a < 2; ++a)
        #pragma unroll
        for (int r = 0; r < 4; ++r) { m1[a][r] = FLT_MAX; m2[a][r] = FLT_MAX; bi[a][r] = 0; }

    __syncthreads();                  // chunk-0 staging + eeL drained

    for (int ch = 0; ch < 4; ++ch) {
        if (ch < 3) {                 // issue next-chunk staging (async)
            const short* src = ehl + (ch + 1) * 16384 + w * 2048 + l * 8;
            short* dst = &eB[(ch + 1) & 1][w * 2048 + l * 8];
            #pragma unroll
            for (int i = 0; i < 4; ++i)
                gload_lds16(src + i * 512, dst + i * 512);
        }

        const short* lb = eB[ch & 1];
        #pragma unroll
        for (int ct = 0; ct < 8; ++ct) {
            const short* fb = lb + ct * 2048 + l * 8;
            const bf16x8 b0 = *(const bf16x8*)(fb);
            const bf16x8 b1 = *(const bf16x8*)(fb + 512);
            const bf16x8 b2 = *(const bf16x8*)(fb + 1024);
            const bf16x8 b3 = *(const bf16x8*)(fb + 1536);

            f32x4 acc0 = {0.f, 0.f, 0.f, 0.f};
            f32x4 acc1 = {0.f, 0.f, 0.f, 0.f};
            acc0 = __builtin_amdgcn_mfma_f32_16x16x32_bf16(aH0[0], b0, acc0, 0, 0, 0);
            acc1 = __builtin_amdgcn_mfma_f32_16x16x32_bf16(aH0[1], b0, acc1, 0, 0, 0);
            acc0 = __builtin_amdgcn_mfma_f32_16x16x32_bf16(aH1[0], b1, acc0, 0, 0, 0);
            acc1 = __builtin_amdgcn_mfma_f32_16x16x32_bf16(aH1[1], b1, acc1, 0, 0, 0);
            acc0 = __builtin_amdgcn_mfma_f32_16x16x32_bf16(aH0[0], b2, acc0, 0, 0, 0);
            acc1 = __builtin_amdgcn_mfma_f32_16x16x32_bf16(aH0[1], b2, acc1, 0, 0, 0);
            acc0 = __builtin_amdgcn_mfma_f32_16x16x32_bf16(aH1[0], b3, acc0, 0, 0, 0);
            acc1 = __builtin_amdgcn_mfma_f32_16x16x32_bf16(aH1[1], b3, acc1, 0, 0, 0);
            acc0 = __builtin_amdgcn_mfma_f32_16x16x32_bf16(aL0[0], b0, acc0, 0, 0, 0);
            acc1 = __builtin_amdgcn_mfma_f32_16x16x32_bf16(aL0[1], b0, acc1, 0, 0, 0);
            acc0 = __builtin_amdgcn_mfma_f32_16x16x32_bf16(aL1[0], b1, acc0, 0, 0, 0);
            acc1 = __builtin_amdgcn_mfma_f32_16x16x32_bf16(aL1[1], b1, acc1, 0, 0, 0);

            const float ek = eeL[ch * 128 + ct * 16 + cl];
            const int code = ch * 128 + ct * 16 + cl;
            #pragma unroll
            for (int r = 0; r < 4; ++r) {
                const float s0 = __fmaf_rn(-2.0f, acc0[r], ek);
                m2[0][r] = __builtin_amdgcn_fmed3f(m1[0][r], m2[0][r], s0);
                bi[0][r] = (s0 < m1[0][r]) ? code : bi[0][r];
                m1[0][r] = fminf(m1[0][r], s0);
                const float s1 = __fmaf_rn(-2.0f, acc1[r], ek);
                m2[1][r] = __builtin_amdgcn_fmed3f(m1[1][r], m2[1][r], s1);
                bi[1][r] = (s1 < m1[1][r]) ? code : bi[1][r];
                m1[1][r] = fminf(m1[1][r], s1);
            }
        }
        __syncthreads();   // drains next-chunk staging; WAR before overwrite
    }

    // merge (m1,m2,bi) across the 16 cl-lanes of each kg group
    #pragma unroll
    for (int a = 0; a < 2; ++a) {
        #pragma unroll
        for (int r = 0; r < 4; ++r) {
            #pragma unroll
            for (int off = 1; off < 16; off <<= 1) {
                const float om1 = __shfl_xor(m1[a][r], off);
                const float om2 = __shfl_xor(m2[a][r], off);
                const int   ob  = __shfl_xor(bi[a][r], off);
                if (om1 < m1[a][r] || (om1 == m1[a][r] && ob < bi[a][r])) {
                    m2[a][r] = fminf(m1[a][r], om2);
                    m1[a][r] = om1; bi[a][r] = ob;
                } else {
                    m2[a][r] = fminf(m2[a][r], om1);
                }
            }
        }
    }

    if (cl == 0) {
        #pragma unroll
        for (int a = 0; a < 2; ++a)
            #pragma unroll
            for (int r = 0; r < 4; ++r) {
                const long long row = wbase + a * 16 + kg * 4 + r;   // D-row map (HW-verified)
                idx[row] = bi[a][r];
                if (m2[a][r] - m1[a][r] < MARGIN) {
                    const int pos = atomicAdd(wl_cnt, 1);
                    if (pos < WL_CAP) wl[pos] = (int)row;
                }
            }
    }
}

// ===========================================================================
// Kernel C: numpy-bit-exact re-resolution, worklist-driven. launch_bounds
// (256,1): za[64]+eb[64] stay in registers (R7's (256,4) forced a spill).
// ===========================================================================
__global__ __launch_bounds__(256, 1) void vq_refine_np_kernel(
    const float* __restrict__ z, const float* __restrict__ emb,
    const float* __restrict__ ee, const int* __restrict__ wl,
    const int* __restrict__ wl_cnt, int* __restrict__ idx)
{
    const int lane = threadIdx.x & 63;
    const int wid  = blockIdx.x * 4 + (threadIdx.x >> 6);
    const int nW   = gridDim.x * 4;
    const int cnt  = min(*wl_cnt, WL_CAP);

    for (int i = wid; i < cnt; i += nW) {
        const long long r = wl[i];

        float za[64];
        const float4* z4 = reinterpret_cast<const float4*>(z + r * D);
        #pragma unroll
        for (int j = 0; j < 16; ++j) {
            float4 tt = z4[j];
            za[4*j] = tt.x; za[4*j+1] = tt.y; za[4*j+2] = tt.z; za[4*j+3] = tt.w;
        }
        const float zz = np_pairwise64_sq(za);

        float best = FLT_MAX; int bk = 0x7fffffff;
        for (int i8 = 0; i8 < 8; ++i8) {
            const int k = (i8 << 6) + lane;          // ascending per lane
            float eb[64];
            const float4* e4 = reinterpret_cast<const float4*>(emb) + k * 16;
            #pragma unroll
            for (int j = 0; j < 16; ++j) {
                float4 tt = e4[j];
                eb[4*j] = tt.x; eb[4*j+1] = tt.y; eb[4*j+2] = tt.z; eb[4*j+3] = tt.w;
            }
            const float G = np_seqfma_dot64(za, eb);
            const float dist = __fadd_rn(__fsub_rn(zz, __fmul_rn(2.0f, G)), ee[k]);
            if (dist < best) { best = dist; bk = k; }
        }
        // cross-lane min, lowest-k tie-break (== numpy first-min)
        #pragma unroll
        for (int off = 32; off; off >>= 1) {
            const float ob = __shfl_xor(best, off);
            const int   ok = __shfl_xor(bk, off);
            if (ob < best || (ob == best && ok < bk)) { best = ob; bk = ok; }
        }
        if (lane == 0) idx[r] = bk;
    }
}

// ===========================================================================
// Kernel B: gather codebook rows, write BOTH tuple outputs (float4).
// ===========================================================================
__global__ void vq_gather_kernel(const float* __restrict__ emb,
                                 const int* __restrict__ idx,
                                 float* __restrict__ out, long long nRows)
{
    const long long c = (long long)blockIdx.x * blockDim.x + threadIdx.x;
    const long long total = nRows * 16;
    if (c >= total) return;
    const long long r = c >> 4;
    const int j = (int)(c & 15);
    const int k = idx[r];
    const float4 val = reinterpret_cast<const float4*>(emb)[k * 16 + j];
    float4* o = reinterpret_cast<float4*>(out);
    o[c] = val;
    o[c + total] = val;
}

// ===========================================================================
extern "C" void kernel_launch(void* const* d_in, const int* in_sizes, int n_in,
                              void* d_out, int out_size, void* d_ws, size_t ws_size,
                              hipStream_t stream) {
    const float* z   = (const float*)d_in[0];   // [N, 64] fp32
    const float* emb = (const float*)d_in[1];   // [512, 64] fp32
    float* out = (float*)d_out;                 // 2 x [N, 64] fp32

    const long long nRows = (long long)in_sizes[0] / D;       // 524288

    char* p = (char*)d_ws;
    int*   idx    = (int*)p;                                      // 2 MB
    float* ee     = (float*)(p + nRows * 4);                      // 2 KB
    short* ehl    = (short*)(p + nRows * 4 + 4096);               // 128 KB
    int*   wl_cnt = (int*)(p + nRows * 4 + 4096 + 131072);        // 4 B
    int*   wl     = (int*)(p + nRows * 4 + 4096 + 131072 + 256);  // 256 KB

    vq_ee_np_kernel<<<1, 512, 0, stream>>>(emb, ee, wl_cnt);
    vq_prep_kernel<<<32, 256, 0, stream>>>(emb, ehl);

    const int scoreBlocks = (int)(nRows / 256);               // 2048
    vq_score_mfma_kernel<<<scoreBlocks, 512, 0, stream>>>(z, ehl, ee, idx, wl, wl_cnt);

    vq_refine_np_kernel<<<512, 256, 0, stream>>>(z, emb, ee, wl, wl_cnt, idx);

    const long long chunks = nRows * 16;
    const int gatherBlocks = (int)((chunks + 255) / 256);     // 32768
    vq_gather_kernel<<<gatherBlocks, 256, 0, stream>>>(emb, idx, out, nRows);
}